// Round 1
// baseline (160.381 us; speedup 1.0000x reference)
//
#include <hip/hip_runtime.h>
#include <stdint.h>

typedef __attribute__((ext_vector_type(8))) short bf16x8;
typedef __attribute__((ext_vector_type(4))) float f32x4;

__device__ __forceinline__ uint32_t f2bf(float f) {
    uint32_t u = __builtin_bit_cast(uint32_t, f);
    u += 0x7fffu + ((u >> 16) & 1u);   // RNE round to bf16
    return u >> 16;
}
__device__ __forceinline__ uint32_t pack2(float a, float b) {
    return f2bf(a) | (f2bf(b) << 16);
}

// Prep: reciprocal norms 1/max(||row||, eps) for que_embed (Q rows) and para_embed (P rows).
__global__ __launch_bounds__(256) void prep_norms(const float* __restrict__ qe,
                                                  const float* __restrict__ pe,
                                                  float* __restrict__ rq,
                                                  float* __restrict__ rp,
                                                  int Q, int Pn) {
    int gw = (blockIdx.x * 256 + threadIdx.x) >> 6;  // one wave per row
    int lane = threadIdx.x & 63;
    if (gw >= Q + Pn) return;
    const float* src = (gw < Q) ? (qe + (size_t)gw * 128) : (pe + (size_t)(gw - Q) * 128);
    float2 v = *(const float2*)(src + lane * 2);
    float s = v.x * v.x + v.y * v.y;
#pragma unroll
    for (int off = 32; off > 0; off >>= 1) s += __shfl_down(s, off, 64);
    if (lane == 0) {
        float r = 1.0f / fmaxf(sqrtf(s), 1e-8f);
        if (gw < Q) rq[gw] = r; else rp[gw - Q] = r;
    }
}

// XOR swizzle: spread 16 rows across all sixteen 16B slots of a 256B LDS row.
#define SWZ(row, byteoff) ((byteoff) ^ (((row) & 15) << 4))

// Fused: C = que_embed(bf16) @ para_embed^T(bf16); cos = C*rq*rp; xor = (qid==pid).
// Block tile 128(q) x 128(p), K=128 fully resident in LDS. 4 waves, each 64x64.
__global__ __launch_bounds__(256, 2) void fused_gemm(
        const float* __restrict__ qe, const float* __restrict__ pe,
        const int* __restrict__ qid, const int* __restrict__ pid,
        const float* __restrict__ rq, const float* __restrict__ rp,
        float* __restrict__ oxor, float* __restrict__ ocos, int Pn) {
    __shared__ unsigned short As[128 * 128];   // que tile  [qrow][k] bf16, swizzled
    __shared__ unsigned short Bs[128 * 128];   // para tile [prow][k] bf16, swizzled
    __shared__ __align__(16) float rqs[128];
    __shared__ __align__(16) float rps[128];
    __shared__ __align__(16) int   qids[128];
    __shared__ __align__(16) int   pids[128];

    const int t = threadIdx.x;
    const int pbase = blockIdx.x * 128;
    const int qbase = blockIdx.y * 128;

    // ---- stage tiles fp32 -> bf16, swizzled ----
    {
        const int row = t >> 1;
        const int k0 = (t & 1) * 64;
        const float* qsrc = qe + (size_t)(qbase + row) * 128 + k0;
        const float* psrc = pe + (size_t)(pbase + row) * 128 + k0;
#pragma unroll
        for (int c = 0; c < 8; ++c) {
            float4 a0 = *(const float4*)(qsrc + c * 8);
            float4 a1 = *(const float4*)(qsrc + c * 8 + 4);
            uint4 pa = { pack2(a0.x, a0.y), pack2(a0.z, a0.w),
                         pack2(a1.x, a1.y), pack2(a1.z, a1.w) };
            int byteoff = (row * 128 + k0 + c * 8) * 2;
            *(uint4*)((char*)As + SWZ(row, byteoff)) = pa;
            float4 b0 = *(const float4*)(psrc + c * 8);
            float4 b1 = *(const float4*)(psrc + c * 8 + 4);
            uint4 pb = { pack2(b0.x, b0.y), pack2(b0.z, b0.w),
                         pack2(b1.x, b1.y), pack2(b1.z, b1.w) };
            *(uint4*)((char*)Bs + SWZ(row, byteoff)) = pb;
        }
        if (t < 128) {
            rqs[t]  = rq[qbase + t];
            qids[t] = qid[qbase + t];
            rps[t]  = rp[pbase + t];
            pids[t] = pid[pbase + t];
        }
    }
    __syncthreads();

    const int lane = t & 63;
    const int w = t >> 6;
    const int wq = (w >> 1) * 64;   // wave's q offset in tile
    const int wp = (w & 1) * 64;    // wave's p offset in tile
    const int lr = lane & 15;       // selects row within A/B LDS tiles
    const int lk = (lane >> 4) * 8; // k offset for this lane group

    f32x4 acc[4][4];
#pragma unroll
    for (int i = 0; i < 4; ++i)
#pragma unroll
        for (int j = 0; j < 4; ++j) acc[i][j] = (f32x4){0.f, 0.f, 0.f, 0.f};

#pragma unroll
    for (int kk = 0; kk < 4; ++kk) {
        bf16x8 af[4], bfr[4];
#pragma unroll
        for (int f = 0; f < 4; ++f) {
            int arow = wq + f * 16 + lr;
            int aoff = (arow * 128 + kk * 32 + lk) * 2;
            af[f] = *(const bf16x8*)((const char*)As + SWZ(arow, aoff));
            int brow = wp + f * 16 + lr;
            int boff = (brow * 128 + kk * 32 + lk) * 2;
            bfr[f] = *(const bf16x8*)((const char*)Bs + SWZ(brow, boff));
        }
        // D = Bfrag(16p x 32k) . Afrag(32k x 16q): lane holds col q = lane&15,
        // rows p = (lane>>4)*4 + reg  -> 4 consecutive p per lane = float4 store.
#pragma unroll
        for (int fq = 0; fq < 4; ++fq)
#pragma unroll
            for (int fp = 0; fp < 4; ++fp)
                acc[fq][fp] = __builtin_amdgcn_mfma_f32_16x16x32_bf16(
                    bfr[fp], af[fq], acc[fq][fp], 0, 0, 0);
    }

    // ---- epilogue: scale + equality, float4 stores along P ----
    const int prg = (lane >> 4) * 4;
#pragma unroll
    for (int fq = 0; fq < 4; ++fq) {
        const int qloc = wq + fq * 16 + lr;
        const size_t qrow = (size_t)(qbase + qloc);
        const float rqv = rqs[qloc];
        const int qv = qids[qloc];
#pragma unroll
        for (int fp = 0; fp < 4; ++fp) {
            const int ploc = wp + fp * 16 + prg;
            const float4 rpv = *(const float4*)&rps[ploc];
            const int4  pv  = *(const int4*)&pids[ploc];
            const f32x4 a = acc[fq][fp];
            const size_t off = qrow * (size_t)Pn + (size_t)(pbase + ploc);
            float4 c4 = { a[0] * rqv * rpv.x, a[1] * rqv * rpv.y,
                          a[2] * rqv * rpv.z, a[3] * rqv * rpv.w };
            float4 x4 = { qv == pv.x ? 1.f : 0.f, qv == pv.y ? 1.f : 0.f,
                          qv == pv.z ? 1.f : 0.f, qv == pv.w ? 1.f : 0.f };
            *(float4*)(ocos + off) = c4;
            *(float4*)(oxor + off) = x4;
        }
    }
}

extern "C" void kernel_launch(void* const* d_in, const int* in_sizes, int n_in,
                              void* d_out, int out_size, void* d_ws, size_t ws_size,
                              hipStream_t stream) {
    const int*   qid = (const int*)d_in[0];
    const int*   pid = (const int*)d_in[1];
    const float* qe  = (const float*)d_in[2];
    const float* pe  = (const float*)d_in[3];
    const int Q  = in_sizes[0];   // 4096
    const int Pn = in_sizes[1];   // 16384

    float* rq = (float*)d_ws;
    float* rp = rq + Q;

    float* oxor = (float*)d_out;
    float* ocos = oxor + (size_t)Q * (size_t)Pn;

    int waves = Q + Pn;
    prep_norms<<<(waves + 3) / 4, 256, 0, stream>>>(qe, pe, rq, rp, Q, Pn);

    dim3 grid(Pn / 128, Q / 128);
    fused_gemm<<<grid, 256, 0, stream>>>(qe, pe, qid, pid, rq, rp, oxor, ocos, Pn);
}